// Round 5
// baseline (3719.650 us; speedup 1.0000x reference)
//
#include <hip/hip_runtime.h>
#include <math.h>

#define B_ 16
#define N_ 256
#define L_ 32
#define NN_ (N_*N_)          // 65536
#define NNL_ (NN_*L_)        // 2097152 elements per batch
#define ANN_ (B_*NN_)        // 1048576
#define POTS_OFF 4096        // float offset where big arrays start
#define NEGINF -1.0e30f
#define TRI_BYTES 131584     // N*(N+1)/2 * 4 = 32896 floats

// ws float layout (float* W = (float*)d_ws):
//   [0 .. 2048)  : 1024 doubles — stats partials [B][32][2]
//   [2048..2080) : stats (mean, invstd) per batch
//   W + POTS_OFF + k*ANN_ for k = 0..5:
//     0: pot1 (start,width)   1: sbar    2: pot2    3: pot3
//     4: hs0  5: he0   (entropy expectation chart, dual layout, global fp32)
//   W + POTS_OFF + 6*ANN_: zres[64]
// Beta-charts live in LDS (triangle-packed, 128.5 KB/block, 1 block/CU).

// ---------------- group shuffle helpers ----------------
template <int G>
__device__ __forceinline__ float gmax(float v) {
#pragma unroll
    for (int k = G / 2; k >= 1; k >>= 1) v = fmaxf(v, __shfl_xor(v, k));
    return v;
}
template <int G>
__device__ __forceinline__ float gsum(float v) {
#pragma unroll
    for (int k = G / 2; k >= 1; k >>= 1) v += __shfl_xor(v, k);
    return v;
}

// ---------------- kernel 1a: per-batch sum/sumsq partials ----------------
__global__ void stats_partial(const float* __restrict__ lp, double* __restrict__ part) {
    int blk = blockIdx.x;            // 0..511 = B*32
    int b = blk >> 5, seg = blk & 31;
    const float4* p4 = (const float4*)(lp + (size_t)b * NNL_ + (size_t)seg * (NNL_ / 32));
    double s = 0.0, ss = 0.0;
    for (int idx = threadIdx.x; idx < (NNL_ / 32 / 4); idx += 256) {
        float4 v = p4[idx];
        s  += (double)v.x + (double)v.y + (double)v.z + (double)v.w;
        ss += (double)v.x * v.x + (double)v.y * v.y + (double)v.z * v.z + (double)v.w * v.w;
    }
    __shared__ double sh0[256], sh1[256];
    sh0[threadIdx.x] = s; sh1[threadIdx.x] = ss;
    __syncthreads();
    for (int off = 128; off > 0; off >>= 1) {
        if (threadIdx.x < off) {
            sh0[threadIdx.x] += sh0[threadIdx.x + off];
            sh1[threadIdx.x] += sh1[threadIdx.x + off];
        }
        __syncthreads();
    }
    if (threadIdx.x == 0) { part[blk * 2] = sh0[0]; part[blk * 2 + 1] = sh1[0]; }
}

// ---------------- kernel 1b: finalize mean/invstd ----------------
__global__ void stats_final(const double* __restrict__ part, float* __restrict__ stats) {
    int b = threadIdx.x;
    if (b >= B_) return;
    double s = 0.0, ss = 0.0;
    for (int k = 0; k < 32; ++k) { s += part[(b * 32 + k) * 2]; ss += part[(b * 32 + k) * 2 + 1]; }
    double n = (double)NNL_;
    double mean = s / n;
    double var = (ss - s * s / n) / (n - 1.0);
    stats[b * 2]     = (float)mean;
    stats[b * 2 + 1] = (float)(1.0 / sqrt(var));
}

// ---------------- kernel 2: label-logsumexp -> span potentials ----------------
__global__ void pots_kernel(const float* __restrict__ lp, const float* __restrict__ evm,
                            const float* __restrict__ stats, float* __restrict__ W) {
    int t = threadIdx.x;
    int c = blockIdx.x * 8 + (t >> 5);
    int lane = t & 31;
    int b = c >> 16;
    int rem = c & (NN_ - 1);
    int i = rem >> 8;
    int w = rem & (N_ - 1);
    if (i + w >= N_) return;                 // lower wrap cells never used
    int j = i + w;
    int base = ((b * NN_ + i * N_ + j) << 5) + lane;
    float mean = stats[b * 2], invstd = stats[b * 2 + 1];
    float x  = (lp[base] - mean) * invstd;
    float em = evm[base];
    // pass1: lse + sbar
    float m1 = gmax<32>(x);
    float e1 = __expf(x - m1);
    float s1 = gsum<32>(e1);
    float n1 = gsum<32>(e1 * x);
    // pass2: smooth mask
    float y  = x + __logf(em + (1.0f - em) * 0.1f + 1e-10f);
    float m2 = gmax<32>(y);
    float s2 = gsum<32>(__expf(y - m2));
    // pass3: hard mask
    float z  = x - 1e6f * (1.0f - em);
    float m3 = gmax<32>(z);
    float s3 = gsum<32>(__expf(z - m3));
    if (lane == 0) {
        int o = b * NN_ + i * N_ + w;        // (start, width) layout
        W[POTS_OFF + 0 * ANN_ + o] = m1 + __logf(s1);
        W[POTS_OFF + 1 * ANN_ + o] = n1 / s1;
        W[POTS_OFF + 2 * ANN_ + o] = m2 + __logf(s2);
        W[POTS_OFF + 3 * ANN_ + o] = m3 + __logf(s3);
    }
}

// triangle row offset: row i holds widths 0..N-1-i
__device__ __forceinline__ int troff(int i) { return i * N_ - ((i * (i - 1)) >> 1); }

// ---------------- width step: G lanes/cell, single-pass register cache -------
// Left operand: chart[troff(i)+u] (lane-stride-1, conflict-free).
// Right operand: diagonal chart[troff(i+u+1)+(w-1-u)], address updated
// incrementally (2nd difference = -G^2) — no per-iteration integer mul.
template <int G, int KMAX, bool EXPM>
__device__ __forceinline__ void step_lds(
    float* __restrict__ chart, const float* __restrict__ pot,
    const float* __restrict__ sbr, float* __restrict__ hs, float* __restrict__ he,
    int w, int cells, int tid)
{
    constexpr int LOGG = (G == 1 ? 0 : G == 4 ? 2 : G == 8 ? 3 : 4);
    constexpr int NG   = 1024 >> LOGG;
    const int group = tid >> LOGG, lane = tid & (G - 1);
    for (int i = group; i < cells; i += NG) {
        const int offi = troff(i);
        const int j = i + w;
        const float pw = pot[i * N_ + w];            // hoisted (VMEM pipe)
        // incremental diagonal addressing
        const int r0 = i + lane + 1;
        int ad = troff(r0) + (w - 1 - lane);
        int dstep = ((N_ - r0) << LOGG) - (G * (G - 1) / 2) - G;
        int al = offi + lane;
        float e[KMAX], hl[KMAX];
        float m = NEGINF;
#pragma unroll
        for (int k = 0; k < KMAX; ++k) {
            const int u = lane + k * G;
            e[k] = NEGINF;
            if (EXPM) hl[k] = 0.f;
            if (u < w) {
                float ev = chart[al] + chart[ad];
                e[k] = ev;
                if (EXPM) hl[k] = hs[i * N_ + u] + he[j * N_ + (w - 1 - u)];
                m = fmaxf(m, ev);
            }
            al += G; ad += dstep; dstep -= G * G;
        }
        if (G > 1) m = gmax<G>(m);
        float s = 0.f, nacc = 0.f;
#pragma unroll
        for (int k = 0; k < KMAX; ++k) {
            float t = __expf(e[k] - m);              // invalid slots -> 0
            s += t;
            if (EXPM) nacc += t * hl[k];
        }
        if (G > 1) { s = gsum<G>(s); if (EXPM) nacc = gsum<G>(nacc); }
        float v = pw + m + __logf(s);
        if (lane == 0) {
            chart[offi + w] = v;
            if (EXPM) {
                float hval = sbr[i * N_ + w] + nacc / s;
                hs[i * N_ + w] = hval;
                he[j * N_ + w] = hval;
            }
        }
    }
}

template <bool EXPM>
__device__ __forceinline__ void cky_loop(
    float* __restrict__ chart, const float* __restrict__ pot,
    const float* __restrict__ sbr, float* __restrict__ hs, float* __restrict__ he,
    int len, int tid)
{
    // width-0 init
    for (int i = tid; i < N_; i += 1024) {
        chart[troff(i)] = pot[i * N_];
        if (EXPM) { float s0 = sbr[i * N_]; hs[i * N_] = s0; he[i * N_] = s0; }
    }
    __syncthreads();
    for (int w = 1; w < len; ++w) {
        int cells = len - w;
        if (w <= 8)       step_lds<1, 8,  EXPM>(chart, pot, sbr, hs, he, w, cells, tid);
        else if (w <= 16) step_lds<4, 4,  EXPM>(chart, pot, sbr, hs, he, w, cells, tid);
        else if (w <= 64) step_lds<8, 8,  EXPM>(chart, pot, sbr, hs, he, w, cells, tid);
        else              step_lds<16, 16, EXPM>(chart, pot, sbr, hs, he, w, cells, tid);
        __syncthreads();
    }
}

// ---------------- kernel 3: all three CKY inside passes, chart in LDS --------
// grid = 3*B blocks: p = bx>>4 in {0(z_full+entropy h), 1(smooth), 2(partial)}
// __launch_bounds__(1024, 4): 1 block/CU -> full 128-VGPR budget, no spill.
__global__ __launch_bounds__(1024, 4)
void cky_all(float* __restrict__ W, const int* __restrict__ lengths) {
    extern __shared__ float chart[];       // 32896 floats, triangle-packed
    int bx = blockIdx.x;
    int p = bx >> 4, b = bx & 15;
    const float* pot; const float* sbr;
    float *hs, *he;
    float* zres = W + POTS_OFF + 6 * ANN_;
    if (p == 0) {
        pot = W + POTS_OFF + 0 * ANN_ + b * NN_;
        sbr = W + POTS_OFF + 1 * ANN_ + b * NN_;
        hs  = W + POTS_OFF + 4 * ANN_ + b * NN_;
        he  = W + POTS_OFF + 5 * ANN_ + b * NN_;
    } else if (p == 1) {
        pot = W + POTS_OFF + 2 * ANN_ + b * NN_; sbr = pot; hs = nullptr; he = nullptr;
    } else {
        pot = W + POTS_OFF + 3 * ANN_ + b * NN_; sbr = pot; hs = nullptr; he = nullptr;
    }
    int len = lengths[b];
    if (len < 1) len = 1;
    if (len > N_) len = N_;
    int tid = threadIdx.x;

    if (p == 0) cky_loop<true >(chart, pot, sbr, hs, he, len, tid);
    else        cky_loop<false>(chart, pot, sbr, hs, he, len, tid);

    if (tid == 0) {
        float root = chart[len - 1];         // beta(0, len-1) = row 0, width len-1
        if (p == 0) { zres[b] = root; zres[48 + b] = hs[len - 1]; }
        else        { zres[p * 16 + b] = root; }
    }
}

// ---------------- kernel 4: combine outputs ----------------
__global__ void combine_kernel(const float* __restrict__ W, float* __restrict__ out) {
    int b = threadIdx.x;
    if (b >= B_) return;
    const float* zres = W + POTS_OFF + 6 * ANN_;
    float zf = zres[b], zs = zres[16 + b], zp = zres[32 + b], hr = zres[48 + b];
    out[b]          = zp - zf;   // log_prob
    out[16 + b]     = zs - zf;   // log_prob_smooth
    out[32 + b]     = zf - hr;   // entropy = z_full - E[sum sbar]
}

extern "C" void kernel_launch(void* const* d_in, const int* in_sizes, int n_in,
                              void* d_out, int out_size, void* d_ws, size_t ws_size,
                              hipStream_t stream) {
    const float* lp      = (const float*)d_in[0];
    // d_in[1] (mask) is unused by the reference
    const int*   lengths = (const int*)d_in[2];
    const float* evm     = (const float*)d_in[3];
    float*  W    = (float*)d_ws;
    double* part = (double*)d_ws;
    float*  stats = W + 2048;
    float*  out  = (float*)d_out;

    // allow 128.5 KB dynamic LDS (host-side attr, graph-safe; idempotent)
    (void)hipFuncSetAttribute((const void*)cky_all,
                              hipFuncAttributeMaxDynamicSharedMemorySize, TRI_BYTES);

    stats_partial<<<B_ * 32, 256, 0, stream>>>(lp, part);
    stats_final<<<1, 64, 0, stream>>>(part, stats);
    pots_kernel<<<(B_ * NN_) / 8, 256, 0, stream>>>(lp, evm, stats, W);
    cky_all<<<3 * B_, 1024, TRI_BYTES, stream>>>(W, lengths);
    combine_kernel<<<1, 64, 0, stream>>>(W, out);
}

// Round 6
// 1720.133 us; speedup vs baseline: 2.1624x; 2.1624x over previous
//
#include <hip/hip_runtime.h>
#include <math.h>

#define B_ 16
#define N_ 256
#define L_ 32
#define NN_ (N_*N_)          // 65536
#define NNL_ (NN_*L_)        // 2097152 elements per batch
#define ANN_ (B_*NN_)        // 1048576
#define POTS_OFF 4096        // float offset where big arrays start
#define NEGINF -1.0e30f

// ws float layout (float* W = (float*)d_ws):
//   [0 .. 2048)  : 1024 doubles — stats partials [B][32][2]
//   [2048..2080) : stats (mean, invstd) per batch
//   W + POTS_OFF + k*ANN_ for k = 0..11:
//     0: pot1 (start,width)   1: sbar    2: pot2    3: pot3
//     4: cs0  5: ce0  6: hs0  7: he0   (z_full pass + expectation semiring)
//     8: cs1  9: ce1                   (z_smooth pass)
//    10: cs2 11: ce2                   (z_partial pass)
//   W + POTS_OFF + 12*ANN_: zres[64]
// Charts in GLOBAL memory, dual (start,width)/(end,width) layout — both split
// operands row-contiguous. LDS chart was tried (r4/r5) and is SLOWER: all
// loads+shuffles+barrier serialize on the per-CU DS pipe; global spreads
// loads on VMEM with deep MLP into warm L2.

// ---------------- group shuffle helpers ----------------
template <int G>
__device__ __forceinline__ float gmax(float v) {
#pragma unroll
    for (int k = G / 2; k >= 1; k >>= 1) v = fmaxf(v, __shfl_xor(v, k));
    return v;
}
template <int G>
__device__ __forceinline__ float gsum(float v) {
#pragma unroll
    for (int k = G / 2; k >= 1; k >>= 1) v += __shfl_xor(v, k);
    return v;
}

// ---------------- kernel 1a: per-batch sum/sumsq partials ----------------
__global__ void stats_partial(const float* __restrict__ lp, double* __restrict__ part) {
    int blk = blockIdx.x;            // 0..511 = B*32
    int b = blk >> 5, seg = blk & 31;
    const float4* p4 = (const float4*)(lp + (size_t)b * NNL_ + (size_t)seg * (NNL_ / 32));
    double s = 0.0, ss = 0.0;
    for (int idx = threadIdx.x; idx < (NNL_ / 32 / 4); idx += 256) {
        float4 v = p4[idx];
        s  += (double)v.x + (double)v.y + (double)v.z + (double)v.w;
        ss += (double)v.x * v.x + (double)v.y * v.y + (double)v.z * v.z + (double)v.w * v.w;
    }
    __shared__ double sh0[256], sh1[256];
    sh0[threadIdx.x] = s; sh1[threadIdx.x] = ss;
    __syncthreads();
    for (int off = 128; off > 0; off >>= 1) {
        if (threadIdx.x < off) {
            sh0[threadIdx.x] += sh0[threadIdx.x + off];
            sh1[threadIdx.x] += sh1[threadIdx.x + off];
        }
        __syncthreads();
    }
    if (threadIdx.x == 0) { part[blk * 2] = sh0[0]; part[blk * 2 + 1] = sh1[0]; }
}

// ---------------- kernel 1b: finalize mean/invstd ----------------
__global__ void stats_final(const double* __restrict__ part, float* __restrict__ stats) {
    int b = threadIdx.x;
    if (b >= B_) return;
    double s = 0.0, ss = 0.0;
    for (int k = 0; k < 32; ++k) { s += part[(b * 32 + k) * 2]; ss += part[(b * 32 + k) * 2 + 1]; }
    double n = (double)NNL_;
    double mean = s / n;
    double var = (ss - s * s / n) / (n - 1.0);
    stats[b * 2]     = (float)mean;
    stats[b * 2 + 1] = (float)(1.0 / sqrt(var));
}

// ---------------- kernel 2: label-lse -> span potentials (thread/cell) -------
// One THREAD per cell: online-softmax over 32 labels, float4 loads, zero
// cross-lane ops (old 32-lane-group version burned ~30 DS-pipe shuffles/cell).
__global__ __launch_bounds__(256)
void pots_kernel(const float* __restrict__ lp, const float* __restrict__ evm,
                 const float* __restrict__ stats, float* __restrict__ W) {
    int t = blockIdx.x * 256 + threadIdx.x;     // 0 .. B*NN-1
    int b = t >> 16;
    int rem = t & (NN_ - 1);
    int i = rem >> 8;
    int w = rem & (N_ - 1);
    if (i + w >= N_) return;
    int j = i + w;
    const float4* xp = (const float4*)(lp  + ((size_t)(b * NN_ + i * N_ + j) << 5));
    const float4* ep = (const float4*)(evm + ((size_t)(b * NN_ + i * N_ + j) << 5));
    float mean = stats[b * 2], invstd = stats[b * 2 + 1];
    float m1 = NEGINF, s1 = 0.f, n1 = 0.f;
    float m2 = NEGINF, s2 = 0.f;
    float m3 = NEGINF, s3 = 0.f;
#pragma unroll
    for (int c = 0; c < 8; ++c) {
        float4 xv = xp[c];
        float4 em = ep[c];
        float x0 = (xv.x - mean) * invstd, x1 = (xv.y - mean) * invstd;
        float x2 = (xv.z - mean) * invstd, x3 = (xv.w - mean) * invstd;
        // pass1: lse + expectation numerator (online rescale per chunk)
        {
            float cm = fmaxf(fmaxf(x0, x1), fmaxf(x2, x3));
            float nm = fmaxf(m1, cm);
            float sc = __expf(m1 - nm);          // first chunk: exp(-inf)=0
            float e0 = __expf(x0 - nm), e1 = __expf(x1 - nm);
            float e2 = __expf(x2 - nm), e3 = __expf(x3 - nm);
            s1 = s1 * sc + (e0 + e1 + e2 + e3);
            n1 = n1 * sc + (e0 * x0 + e1 * x1 + e2 * x2 + e3 * x3);
            m1 = nm;
        }
        // pass2: smooth mask  y = x + log(0.1 + 0.9*em + 1e-10)
        {
            float y0 = x0 + __logf(fmaf(em.x, 0.9f, 0.1f) + 1e-10f);
            float y1 = x1 + __logf(fmaf(em.y, 0.9f, 0.1f) + 1e-10f);
            float y2 = x2 + __logf(fmaf(em.z, 0.9f, 0.1f) + 1e-10f);
            float y3 = x3 + __logf(fmaf(em.w, 0.9f, 0.1f) + 1e-10f);
            float cm = fmaxf(fmaxf(y0, y1), fmaxf(y2, y3));
            float nm = fmaxf(m2, cm);
            float sc = __expf(m2 - nm);
            s2 = s2 * sc + __expf(y0 - nm) + __expf(y1 - nm) + __expf(y2 - nm) + __expf(y3 - nm);
            m2 = nm;
        }
        // pass3: hard mask  z = x - 1e6*(1-em)
        {
            float z0 = fmaf(em.x, 1e6f, x0 - 1e6f);
            float z1 = fmaf(em.y, 1e6f, x1 - 1e6f);
            float z2 = fmaf(em.z, 1e6f, x2 - 1e6f);
            float z3 = fmaf(em.w, 1e6f, x3 - 1e6f);
            float cm = fmaxf(fmaxf(z0, z1), fmaxf(z2, z3));
            float nm = fmaxf(m3, cm);
            float sc = __expf(m3 - nm);
            s3 = s3 * sc + __expf(z0 - nm) + __expf(z1 - nm) + __expf(z2 - nm) + __expf(z3 - nm);
            m3 = nm;
        }
    }
    int o = b * NN_ + i * N_ + w;                // (start, width) layout
    W[POTS_OFF + 0 * ANN_ + o] = m1 + __logf(s1);
    W[POTS_OFF + 1 * ANN_ + o] = n1 / s1;
    W[POTS_OFF + 2 * ANN_ + o] = m2 + __logf(s2);
    W[POTS_OFF + 3 * ANN_ + o] = m3 + __logf(s3);
}

// ---------------- width step: G lanes/cell, 4 consecutive splits per lane ----
// Lane l owns u = 4l + 4G*k: left (cs) + hs are aligned float4 loads; right
// (ce) + he are 4 contiguous-descending scalars (same cache line). All
// addresses independent per k — loads issue with full MLP, one wait per cell.
template <int G, int KB, bool EXPM>
__device__ __forceinline__ void step_g(
    const float* __restrict__ pot, const float* __restrict__ sbr,
    float* __restrict__ cs, float* __restrict__ ce,
    float* __restrict__ hs, float* __restrict__ he,
    int w, int cells, int tid)
{
    constexpr int LOGG = (G == 1 ? 0 : G == 4 ? 2 : G == 8 ? 3 : 4);
    constexpr int NG   = 1024 >> LOGG;
    const int group = tid >> LOGG, lane = tid & (G - 1);
    const int u0 = lane << 2;
    const int kmax = (w + 4 * G - 1) >> (LOGG + 2);
    for (int i = group; i < cells; i += NG) {
        const int j = i + w;
        const float* csr = cs + i * N_;
        const float* cer = ce + j * N_;
        const float* hsr = hs + i * N_;
        const float* her = he + j * N_;
        const float pw = pot[i * N_ + w];
        float4 ev[KB], hl[KB];
        float m = NEGINF;
#pragma unroll
        for (int k = 0; k < KB; ++k) {
            ev[k].x = NEGINF; ev[k].y = NEGINF; ev[k].z = NEGINF; ev[k].w = NEGINF;
            if (EXPM) { hl[k].x = 0.f; hl[k].y = 0.f; hl[k].z = 0.f; hl[k].w = 0.f; }
            if (k < kmax) {
                const int u = u0 + (k << (LOGG + 2));
                const int r0 = w - 1 - u;        // may go negative for masked slots:
                float4 Lv = *(const float4*)(csr + u);       // row has N_=256 entries, u<=252: safe
                float R0 = cer[r0], R1 = cer[r0 - 1], R2 = cer[r0 - 2], R3 = cer[r0 - 3];
                float4 tv;                       // (j>=w => cer[-k] stays inside the chart array)
                tv.x = Lv.x + R0; tv.y = Lv.y + R1; tv.z = Lv.z + R2; tv.w = Lv.w + R3;
                tv.x = (u     < w) ? tv.x : NEGINF;
                tv.y = (u + 1 < w) ? tv.y : NEGINF;
                tv.z = (u + 2 < w) ? tv.z : NEGINF;
                tv.w = (u + 3 < w) ? tv.w : NEGINF;
                ev[k] = tv;
                m = fmaxf(m, fmaxf(fmaxf(tv.x, tv.y), fmaxf(tv.z, tv.w)));
                if (EXPM) {
                    float4 Hs = *(const float4*)(hsr + u);
                    float H0 = her[r0], H1 = her[r0 - 1], H2 = her[r0 - 2], H3 = her[r0 - 3];
                    hl[k].x = Hs.x + H0; hl[k].y = Hs.y + H1;   // garbage in masked slots is
                    hl[k].z = Hs.z + H2; hl[k].w = Hs.w + H3;   // multiplied by exp(NEGINF)=0
                }
            }
        }
        if (G > 1) m = gmax<G>(m);
        float s = 0.f, nacc = 0.f;
#pragma unroll
        for (int k = 0; k < KB; ++k) {
            float a = __expf(ev[k].x - m), bq = __expf(ev[k].y - m);
            float c = __expf(ev[k].z - m), d  = __expf(ev[k].w - m);
            s += (a + bq) + (c + d);
            if (EXPM) nacc += a * hl[k].x + bq * hl[k].y + c * hl[k].z + d * hl[k].w;
        }
        if (G > 1) { s = gsum<G>(s); if (EXPM) nacc = gsum<G>(nacc); }
        float v = pw + m + __logf(s);
        if (lane == 0) {
            cs[i * N_ + w] = v;
            ce[j * N_ + w] = v;
            if (EXPM) {
                float hval = sbr[i * N_ + w] + nacc / s;
                hs[i * N_ + w] = hval;
                he[j * N_ + w] = hval;
            }
        }
    }
}

template <bool EXPM>
__device__ __forceinline__ void cky_loop(
    const float* __restrict__ pot, const float* __restrict__ sbr,
    float* __restrict__ cs, float* __restrict__ ce,
    float* __restrict__ hs, float* __restrict__ he,
    int len, int tid)
{
    for (int i = tid; i < N_; i += 1024) {
        float v = pot[i * N_];
        cs[i * N_] = v; ce[i * N_] = v;
        if (EXPM) { float s0 = sbr[i * N_]; hs[i * N_] = s0; he[i * N_] = s0; }
    }
    __syncthreads();
    for (int w = 1; w < len; ++w) {
        int cells = len - w;
        if (w <= 8)       step_g<1,  2, EXPM>(pot, sbr, cs, ce, hs, he, w, cells, tid);
        else if (w <= 16) step_g<4,  1, EXPM>(pot, sbr, cs, ce, hs, he, w, cells, tid);
        else if (w <= 64) step_g<8,  2, EXPM>(pot, sbr, cs, ce, hs, he, w, cells, tid);
        else              step_g<16, 4, EXPM>(pot, sbr, cs, ce, hs, he, w, cells, tid);
        __syncthreads();
    }
}

// ---------------- kernel 3: all three CKY inside passes in one launch --------
// grid = 3*B blocks: p = bx>>4 in {0(z_full+entropy h), 1(smooth), 2(partial)}
__global__ __launch_bounds__(1024, 4)
void cky_all(float* __restrict__ W, const int* __restrict__ lengths) {
    int bx = blockIdx.x;
    int p = bx >> 4, b = bx & 15;
    const float* pot; const float* sbr;
    float *cs, *ce, *hs, *he;
    float* zres = W + POTS_OFF + 12 * ANN_;
    if (p == 0) {
        pot = W + POTS_OFF + 0 * ANN_ + b * NN_;
        sbr = W + POTS_OFF + 1 * ANN_ + b * NN_;
        cs  = W + POTS_OFF + 4 * ANN_ + b * NN_;
        ce  = W + POTS_OFF + 5 * ANN_ + b * NN_;
        hs  = W + POTS_OFF + 6 * ANN_ + b * NN_;
        he  = W + POTS_OFF + 7 * ANN_ + b * NN_;
    } else if (p == 1) {
        pot = W + POTS_OFF + 2 * ANN_ + b * NN_; sbr = pot;
        cs  = W + POTS_OFF + 8 * ANN_ + b * NN_;
        ce  = W + POTS_OFF + 9 * ANN_ + b * NN_;
        hs = cs; he = ce;
    } else {
        pot = W + POTS_OFF + 3 * ANN_ + b * NN_; sbr = pot;
        cs  = W + POTS_OFF + 10 * ANN_ + b * NN_;
        ce  = W + POTS_OFF + 11 * ANN_ + b * NN_;
        hs = cs; he = ce;
    }
    int len = lengths[b];
    if (len < 1) len = 1;
    if (len > N_) len = N_;
    int tid = threadIdx.x;

    if (p == 0) cky_loop<true >(pot, sbr, cs, ce, hs, he, len, tid);
    else        cky_loop<false>(pot, sbr, cs, ce, hs, he, len, tid);

    if (tid == 0) {
        float root = cs[len - 1];            // cs[0][len-1]
        if (p == 0) { zres[b] = root; zres[48 + b] = hs[len - 1]; }
        else        { zres[p * 16 + b] = root; }
    }
}

// ---------------- kernel 4: combine outputs ----------------
__global__ void combine_kernel(const float* __restrict__ W, float* __restrict__ out) {
    int b = threadIdx.x;
    if (b >= B_) return;
    const float* zres = W + POTS_OFF + 12 * ANN_;
    float zf = zres[b], zs = zres[16 + b], zp = zres[32 + b], hr = zres[48 + b];
    out[b]          = zp - zf;   // log_prob
    out[16 + b]     = zs - zf;   // log_prob_smooth
    out[32 + b]     = zf - hr;   // entropy = z_full - E[sum sbar]
}

extern "C" void kernel_launch(void* const* d_in, const int* in_sizes, int n_in,
                              void* d_out, int out_size, void* d_ws, size_t ws_size,
                              hipStream_t stream) {
    const float* lp      = (const float*)d_in[0];
    // d_in[1] (mask) is unused by the reference
    const int*   lengths = (const int*)d_in[2];
    const float* evm     = (const float*)d_in[3];
    float*  W    = (float*)d_ws;
    double* part = (double*)d_ws;
    float*  stats = W + 2048;
    float*  out  = (float*)d_out;

    stats_partial<<<B_ * 32, 256, 0, stream>>>(lp, part);
    stats_final<<<1, 64, 0, stream>>>(part, stats);
    pots_kernel<<<(B_ * NN_) / 256, 256, 0, stream>>>(lp, evm, stats, W);
    cky_all<<<3 * B_, 1024, 0, stream>>>(W, lengths);
    combine_kernel<<<1, 64, 0, stream>>>(W, out);
}